// Round 5
// baseline (57.299 us; speedup 1.0000x reference)
//
#include <hip/hip_runtime.h>
#include <math.h>

// Problem constants: B=8, T=512, DIM=9, UPP=512
#define BB 8
#define TT 512
#define DIMN 9
#define UPP 512
#define LL (TT * UPP)                     // 262144 = 2^18
#define TOTAL (BB * LL * DIMN)            // 18,874,368
#define SRATE 48000.0

typedef float v4f __attribute__((ext_vector_type(4)));   // clang vector: OK for nontemporal builtins

__device__ __forceinline__ double dfrac(double x) { return x - floor(x); }

// Kernel 1: frame-level phase scan, one WAVE per (b,d), no barriers.
//   rp[b][t][d] = frac(rad)                 (per-sample increment, revolutions)
//   cf[b][t][d] = frac(UPP * sum_{s<t} rp)  (phase before frame t, mod 1)
__global__ void __launch_bounds__(256) frame_scan_wave(
        const float* __restrict__ f0,
        const float* __restrict__ rand_ini,
        float* __restrict__ rp_out,
        float* __restrict__ cf_out) {
    const int wave = blockIdx.x * 4 + (threadIdx.x >> 6);   // 0..71
    const int lane = threadIdx.x & 63;
    if (wave >= BB * DIMN) return;
    const int b = wave / DIMN;
    const int d = wave % DIMN;
    const int t0 = lane * 8;

    v4f fA = *reinterpret_cast<const v4f*>(f0 + b * TT + t0);
    v4f fB = *reinterpret_cast<const v4f*>(f0 + b * TT + t0 + 4);
    float fv[8] = {fA.x, fA.y, fA.z, fA.w, fB.x, fB.y, fB.z, fB.w};

    const double mult = (double)(d + 1) * (1.0 / SRATE);
    double rpj[8], pex[8];
    double s = 0.0;
#pragma unroll
    for (int j = 0; j < 8; ++j) {
        double raw = (double)fv[j] * mult;                  // < 0.075, first %1 identity
        if (lane == 0 && j == 0) raw += (double)rand_ini[b * DIMN + d];
        double rp = dfrac(raw);
        rpj[j] = rp;
        pex[j] = s;
        s += (double)UPP * rp;
    }
    double incl = s;
#pragma unroll
    for (int off = 1; off < 64; off <<= 1) {
        double up = __shfl_up(incl, off);
        if (lane >= off) incl += up;
    }
    const double E = incl - s;
#pragma unroll
    for (int j = 0; j < 8; ++j) {
        int fidx = (b * TT + t0 + j) * DIMN + d;
        rp_out[fidx] = (float)rpj[j];
        cf_out[fidx] = (float)dfrac(E + pex[j]);
    }
}

// Kernel 2: 4 consecutive flat elements per thread, all f32, v_fract+v_sin.
// All big streams nontemporal (zero reuse); rp/cf/f0 stay cached (heavy reuse).
__global__ void __launch_bounds__(256) sine_out_kernel(
        const float* __restrict__ f0,
        const float* __restrict__ noise_randn,
        const float* __restrict__ rp,
        const float* __restrict__ cf,
        float* __restrict__ out0,
        float* __restrict__ out1,
        float* __restrict__ out2) {
    unsigned gid  = blockIdx.x * blockDim.x + threadIdx.x;
    unsigned base = gid * 4u;

    v4f nz4 = __builtin_nontemporal_load(
        reinterpret_cast<const v4f*>(noise_randn + base));

    unsigned d  = base % 9u;
    unsigned bl = base / 9u;          // b*LL + l

    float o0[4], o2[4];
#pragma unroll
    for (int j = 0; j < 4; ++j) {
        unsigned b = bl >> 18;
        unsigned l = bl & (LL - 1u);
        unsigned t = l >> 9;
        unsigned k = l & 511u;
        unsigned fidx = (b * TT + t) * DIMN + d;

        float r = rp[fidx];
        float c = cf[fidx];
        float ph = fmaf((float)(k + 1), r, c);
        float ff = __builtin_amdgcn_fractf(ph);          // v_fract_f32
        float s  = __builtin_amdgcn_sinf(ff) * 0.1f;     // v_sin_f32: sin(2*pi*x)

        float f0v = f0[b * TT + t];
        bool  v   = f0v > 0.0f;
        float nz  = (v ? 0.003f : (0.1f / 3.0f)) * nz4[j];
        o0[j] = (v ? s : 0.0f) + nz;
        o2[j] = nz;

        if (++d == 9u) { d = 0u; ++bl; }
    }
    v4f v0 = {o0[0], o0[1], o0[2], o0[3]};
    v4f v2 = {o2[0], o2[1], o2[2], o2[3]};
    __builtin_nontemporal_store(v0, reinterpret_cast<v4f*>(out0 + base));
    __builtin_nontemporal_store(v2, reinterpret_cast<v4f*>(out2 + base));

    // fused uv: B*L/4 float4 stores, done by the first 2048 blocks
    if (gid < (BB * LL) / 4u) {
        unsigned i4 = gid * 4u;                  // 4 samples, same frame (512%4==0)
        unsigned b = i4 >> 18;
        unsigned l = i4 & (LL - 1u);
        unsigned t = l >> 9;
        float uvf = (f0[b * TT + t] > 0.0f) ? 1.0f : 0.0f;
        v4f vu = {uvf, uvf, uvf, uvf};
        __builtin_nontemporal_store(vu, reinterpret_cast<v4f*>(out1 + i4));
    }
}

extern "C" void kernel_launch(void* const* d_in, const int* in_sizes, int n_in,
                              void* d_out, int out_size, void* d_ws, size_t ws_size,
                              hipStream_t stream) {
    const float* f0          = (const float*)d_in[0];   // [B, T]
    const float* rand_ini    = (const float*)d_in[1];   // [B, DIM]
    const float* noise_randn = (const float*)d_in[2];   // [B, L, DIM]
    // d_in[3] = upp (scalar 512) — hardcoded

    float* rp = (float*)d_ws;                           // B*T*DIM f32
    float* cf = rp + (size_t)BB * TT * DIMN;            // B*T*DIM f32

    float* out0 = (float*)d_out;                        // [B, L, DIM]
    float* out1 = out0 + (size_t)BB * LL * DIMN;        // [B, L]
    float* out2 = out1 + (size_t)BB * LL;               // [B, L, DIM]

    frame_scan_wave<<<18, 256, 0, stream>>>(f0, rand_ini, rp, cf);

    const int block = 256;
    const unsigned grid2 = TOTAL / 4 / block;           // 18432
    sine_out_kernel<<<grid2, block, 0, stream>>>(f0, noise_randn, rp, cf,
                                                 out0, out1, out2);
}

// Round 6
// 49.048 us; speedup vs baseline: 1.1682x; 1.1682x over previous
//
#include <hip/hip_runtime.h>
#include <math.h>

// Problem constants: B=8, T=512, DIM=9, UPP=512
#define BB 8
#define TT 512
#define DIMN 9
#define UPP 512
#define LL (TT * UPP)                     // 262144 = 2^18
#define TOTAL (BB * LL * DIMN)            // 18,874,368 (divisible by 8*256)
#define SRATE 48000.0

typedef float v4f __attribute__((ext_vector_type(4)));

__device__ __forceinline__ double dfrac(double x) { return x - floor(x); }

// Kernel 1: frame-level phase scan, one WAVE per (b,d), no barriers.
//   rp[b][t][d] = frac(rad)                 (per-sample increment, revolutions)
//   cf[b][t][d] = frac(UPP * sum_{s<t} rp)  (phase before frame t, mod 1)
__global__ void __launch_bounds__(256) frame_scan_wave(
        const float* __restrict__ f0,
        const float* __restrict__ rand_ini,
        float* __restrict__ rp_out,
        float* __restrict__ cf_out) {
    const int wave = blockIdx.x * 4 + (threadIdx.x >> 6);   // 0..71
    const int lane = threadIdx.x & 63;
    if (wave >= BB * DIMN) return;
    const int b = wave / DIMN;
    const int d = wave % DIMN;
    const int t0 = lane * 8;

    v4f fA = *reinterpret_cast<const v4f*>(f0 + b * TT + t0);
    v4f fB = *reinterpret_cast<const v4f*>(f0 + b * TT + t0 + 4);
    float fv[8] = {fA.x, fA.y, fA.z, fA.w, fB.x, fB.y, fB.z, fB.w};

    const double mult = (double)(d + 1) * (1.0 / SRATE);
    double rpj[8], pex[8];
    double s = 0.0;
#pragma unroll
    for (int j = 0; j < 8; ++j) {
        double raw = (double)fv[j] * mult;                  // < 0.075, first %1 identity
        if (lane == 0 && j == 0) raw += (double)rand_ini[b * DIMN + d];
        double rp = dfrac(raw);
        rpj[j] = rp;
        pex[j] = s;
        s += (double)UPP * rp;
    }
    double incl = s;
#pragma unroll
    for (int off = 1; off < 64; off <<= 1) {
        double up = __shfl_up(incl, off);
        if (lane >= off) incl += up;
    }
    const double E = incl - s;
#pragma unroll
    for (int j = 0; j < 8; ++j) {
        int fidx = (b * TT + t0 + j) * DIMN + d;
        rp_out[fidx] = (float)rpj[j];
        cf_out[fidx] = (float)dfrac(E + pex[j]);
    }
}

// Kernel 2: 8 consecutive flat elements per thread, all f32, v_fract+v_sin.
// Both noise loads issued before compute (2x MLP). All stores cached (NT regressed).
__global__ void __launch_bounds__(256) sine_out_kernel(
        const float* __restrict__ f0,
        const float* __restrict__ noise_randn,
        const float* __restrict__ rp,
        const float* __restrict__ cf,
        float* __restrict__ out0,
        float* __restrict__ out1,
        float* __restrict__ out2) {
    unsigned gid  = blockIdx.x * blockDim.x + threadIdx.x;
    unsigned base = gid * 8u;

    v4f nzA = *reinterpret_cast<const v4f*>(noise_randn + base);
    v4f nzB = *reinterpret_cast<const v4f*>(noise_randn + base + 4);
    float nzv[8] = {nzA.x, nzA.y, nzA.z, nzA.w, nzB.x, nzB.y, nzB.z, nzB.w};

    unsigned d  = base % 9u;
    unsigned bl = base / 9u;          // b*LL + l

    float o0[8], o2[8];
#pragma unroll
    for (int j = 0; j < 8; ++j) {
        unsigned b = bl >> 18;
        unsigned l = bl & (LL - 1u);
        unsigned t = l >> 9;
        unsigned k = l & 511u;
        unsigned fidx = (b * TT + t) * DIMN + d;

        float r = rp[fidx];
        float c = cf[fidx];
        float ph = fmaf((float)(k + 1), r, c);
        float ff = __builtin_amdgcn_fractf(ph);          // v_fract_f32
        float s  = __builtin_amdgcn_sinf(ff) * 0.1f;     // v_sin_f32: sin(2*pi*x)

        float f0v = f0[b * TT + t];
        bool  v   = f0v > 0.0f;
        float nz  = (v ? 0.003f : (0.1f / 3.0f)) * nzv[j];
        o0[j] = (v ? s : 0.0f) + nz;
        o2[j] = nz;

        if (++d == 9u) { d = 0u; ++bl; }
    }
    v4f s0A = {o0[0], o0[1], o0[2], o0[3]}, s0B = {o0[4], o0[5], o0[6], o0[7]};
    v4f s2A = {o2[0], o2[1], o2[2], o2[3]}, s2B = {o2[4], o2[5], o2[6], o2[7]};
    *reinterpret_cast<v4f*>(out0 + base)     = s0A;
    *reinterpret_cast<v4f*>(out0 + base + 4) = s0B;
    *reinterpret_cast<v4f*>(out2 + base)     = s2A;
    *reinterpret_cast<v4f*>(out2 + base + 4) = s2B;

    // fused uv: first 1024 blocks write 8 samples each (same frame: 512%8==0)
    if (gid < (BB * LL) / 8u) {
        unsigned i8 = gid * 8u;
        unsigned b = i8 >> 18;
        unsigned l = i8 & (LL - 1u);
        unsigned t = l >> 9;
        float uvf = (f0[b * TT + t] > 0.0f) ? 1.0f : 0.0f;
        v4f vu = {uvf, uvf, uvf, uvf};
        *reinterpret_cast<v4f*>(out1 + i8)     = vu;
        *reinterpret_cast<v4f*>(out1 + i8 + 4) = vu;
    }
}

extern "C" void kernel_launch(void* const* d_in, const int* in_sizes, int n_in,
                              void* d_out, int out_size, void* d_ws, size_t ws_size,
                              hipStream_t stream) {
    const float* f0          = (const float*)d_in[0];   // [B, T]
    const float* rand_ini    = (const float*)d_in[1];   // [B, DIM]
    const float* noise_randn = (const float*)d_in[2];   // [B, L, DIM]
    // d_in[3] = upp (scalar 512) — hardcoded

    float* rp = (float*)d_ws;                           // B*T*DIM f32
    float* cf = rp + (size_t)BB * TT * DIMN;            // B*T*DIM f32

    float* out0 = (float*)d_out;                        // [B, L, DIM]
    float* out1 = out0 + (size_t)BB * LL * DIMN;        // [B, L]
    float* out2 = out1 + (size_t)BB * LL;               // [B, L, DIM]

    frame_scan_wave<<<18, 256, 0, stream>>>(f0, rand_ini, rp, cf);

    const int block = 256;
    const unsigned grid2 = TOTAL / 8 / block;           // 9216
    sine_out_kernel<<<grid2, block, 0, stream>>>(f0, noise_randn, rp, cf,
                                                 out0, out1, out2);
}

// Round 7
// 46.086 us; speedup vs baseline: 1.2433x; 1.0643x over previous
//
#include <hip/hip_runtime.h>
#include <math.h>

// Problem constants: B=8, T=512, DIM=9, UPP=512
#define BB 8
#define TT 512
#define DIMN 9
#define UPP 512
#define LL (TT * UPP)                     // 262144 = 2^18
#define TOTAL (BB * LL * DIMN)            // 18,874,368
#define SRATE 48000.0

typedef float v4f __attribute__((ext_vector_type(4)));

__device__ __forceinline__ double dfrac(double x) { return x - floor(x); }

// Kernel 1: frame-level phase scan, one WAVE per (b,d), no barriers.
//   rp[b][t][d] = frac(rad)                 (per-sample increment, revolutions)
//   cf[b][t][d] = frac(UPP * sum_{s<t} rp)  (phase before frame t, mod 1)
__global__ void __launch_bounds__(256) frame_scan_wave(
        const float* __restrict__ f0,
        const float* __restrict__ rand_ini,
        float* __restrict__ rp_out,
        float* __restrict__ cf_out) {
    const int wave = blockIdx.x * 4 + (threadIdx.x >> 6);   // 0..71
    const int lane = threadIdx.x & 63;
    if (wave >= BB * DIMN) return;
    const int b = wave / DIMN;
    const int d = wave % DIMN;
    const int t0 = lane * 8;

    v4f fA = *reinterpret_cast<const v4f*>(f0 + b * TT + t0);
    v4f fB = *reinterpret_cast<const v4f*>(f0 + b * TT + t0 + 4);
    float fv[8] = {fA.x, fA.y, fA.z, fA.w, fB.x, fB.y, fB.z, fB.w};

    const double mult = (double)(d + 1) * (1.0 / SRATE);
    double rpj[8], pex[8];
    double s = 0.0;
#pragma unroll
    for (int j = 0; j < 8; ++j) {
        double raw = (double)fv[j] * mult;                  // < 0.075, first %1 identity
        if (lane == 0 && j == 0) raw += (double)rand_ini[b * DIMN + d];
        double rp = dfrac(raw);
        rpj[j] = rp;
        pex[j] = s;
        s += (double)UPP * rp;
    }
    double incl = s;
#pragma unroll
    for (int off = 1; off < 64; off <<= 1) {
        double up = __shfl_up(incl, off);
        if (lane >= off) incl += up;
    }
    const double E = incl - s;
#pragma unroll
    for (int j = 0; j < 8; ++j) {
        int fidx = (b * TT + t0 + j) * DIMN + d;
        rp_out[fidx] = (float)rpj[j];
        cf_out[fidx] = (float)dfrac(E + pex[j]);
    }
}

// Kernel 2: 4 consecutive flat elements per thread (R3 shape — best measured).
// uv stores spread uniformly: every 9th block handles one uv chunk.
__global__ void __launch_bounds__(256) sine_out_kernel(
        const float* __restrict__ f0,
        const float* __restrict__ noise_randn,
        const float* __restrict__ rp,
        const float* __restrict__ cf,
        float* __restrict__ out0,
        float* __restrict__ out1,
        float* __restrict__ out2) {
    unsigned gid  = blockIdx.x * blockDim.x + threadIdx.x;
    unsigned base = gid * 4u;

    v4f nz4 = *reinterpret_cast<const v4f*>(noise_randn + base);

    unsigned d  = base % 9u;
    unsigned bl = base / 9u;          // b*LL + l

    float o0[4], o2[4];
#pragma unroll
    for (int j = 0; j < 4; ++j) {
        unsigned b = bl >> 18;
        unsigned l = bl & (LL - 1u);
        unsigned t = l >> 9;
        unsigned k = l & 511u;
        unsigned fidx = (b * TT + t) * DIMN + d;

        float r = rp[fidx];
        float c = cf[fidx];
        float ph = fmaf((float)(k + 1), r, c);
        float ff = __builtin_amdgcn_fractf(ph);          // v_fract_f32
        float s  = __builtin_amdgcn_sinf(ff) * 0.1f;     // v_sin_f32: sin(2*pi*x)

        float f0v = f0[b * TT + t];
        bool  v   = f0v > 0.0f;
        float nz  = (v ? 0.003f : (0.1f / 3.0f)) * nz4[j];
        o0[j] = (v ? s : 0.0f) + nz;
        o2[j] = nz;

        if (++d == 9u) { d = 0u; ++bl; }
    }
    v4f v0 = {o0[0], o0[1], o0[2], o0[3]};
    v4f v2 = {o2[0], o2[1], o2[2], o2[3]};
    *reinterpret_cast<v4f*>(out0 + base) = v0;
    *reinterpret_cast<v4f*>(out2 + base) = v2;

    // fused uv: 18432 blocks / 9 = 2048 uv-blocks, spread uniformly across the grid
    if (blockIdx.x % 9u == 0u) {
        unsigned ug = (blockIdx.x / 9u) * blockDim.x + threadIdx.x;  // 0..524287
        unsigned i4 = ug * 4u;                   // 4 samples, same frame (512%4==0)
        unsigned b = i4 >> 18;
        unsigned l = i4 & (LL - 1u);
        unsigned t = l >> 9;
        float uvf = (f0[b * TT + t] > 0.0f) ? 1.0f : 0.0f;
        v4f vu = {uvf, uvf, uvf, uvf};
        *reinterpret_cast<v4f*>(out1 + i4) = vu;
    }
}

extern "C" void kernel_launch(void* const* d_in, const int* in_sizes, int n_in,
                              void* d_out, int out_size, void* d_ws, size_t ws_size,
                              hipStream_t stream) {
    const float* f0          = (const float*)d_in[0];   // [B, T]
    const float* rand_ini    = (const float*)d_in[1];   // [B, DIM]
    const float* noise_randn = (const float*)d_in[2];   // [B, L, DIM]
    // d_in[3] = upp (scalar 512) — hardcoded

    float* rp = (float*)d_ws;                           // B*T*DIM f32
    float* cf = rp + (size_t)BB * TT * DIMN;            // B*T*DIM f32

    float* out0 = (float*)d_out;                        // [B, L, DIM]
    float* out1 = out0 + (size_t)BB * LL * DIMN;        // [B, L]
    float* out2 = out1 + (size_t)BB * LL;               // [B, L, DIM]

    frame_scan_wave<<<18, 256, 0, stream>>>(f0, rand_ini, rp, cf);

    const int block = 256;
    const unsigned grid2 = TOTAL / 4 / block;           // 18432
    sine_out_kernel<<<grid2, block, 0, stream>>>(f0, noise_randn, rp, cf,
                                                 out0, out1, out2);
}